// Round 1
// baseline (251.838 us; speedup 1.0000x reference)
//
#include <hip/hip_runtime.h>
#include <hip/hip_bf16.h>
#include <stdint.h>

#define T_SEQ 336
#define T_PAD 352   // K padded to multiple of BK
#define P_LEN 720
#define P_PAD 768   // M padded to multiple of BM
#define C_LEN 1782
#define NB    64

#define BM 128
#define BN 128
#define BK 32
#define XP 40       // xT row pitch (elems): breaks bank conflicts, keeps 16B align

typedef __attribute__((ext_vector_type(4))) float f32x4;
typedef __attribute__((ext_vector_type(8))) short s16x8;

__device__ __forceinline__ unsigned short f2bf(float f) {
  unsigned int u = __builtin_bit_cast(unsigned int, f);
  u += 0x7FFFu + ((u >> 16) & 1u);   // round-to-nearest-even
  return (unsigned short)(u >> 16);
}

// Weff[p,k] = Ws[p,k] + (1/5)*sum_t (Wt-Ws)[p,t] * c(t,k); zero-padded to [768][352].
// c(t,k)=1 for |t-k|<=2 (interior k); edges k=0 / k=335 get weights 3,2,1.
__global__ __launch_bounds__(128) void prep_kernel(
    const float* __restrict__ Ws, const float* __restrict__ bs,
    const float* __restrict__ Wt, const float* __restrict__ bt,
    unsigned short* __restrict__ weff, float* __restrict__ bias) {
  int p = blockIdx.x;
  const float* wsr = Ws + (size_t)p * T_SEQ;
  const float* wtr = Wt + (size_t)p * T_SEQ;
  for (int k = threadIdx.x; k < T_PAD; k += blockDim.x) {
    float val = 0.f;
    if (p < P_LEN && k < T_SEQ) {
      float d;
      if (k == 0) {
        d = 3.f*(wtr[0]-wsr[0]) + 2.f*(wtr[1]-wsr[1]) + (wtr[2]-wsr[2]);
      } else if (k == T_SEQ-1) {
        d = 3.f*(wtr[T_SEQ-1]-wsr[T_SEQ-1]) + 2.f*(wtr[T_SEQ-2]-wsr[T_SEQ-2])
            + (wtr[T_SEQ-3]-wsr[T_SEQ-3]);
      } else {
        int lo = (k-2 < 0) ? 0 : k-2;
        int hi = (k+2 > T_SEQ-1) ? T_SEQ-1 : k+2;
        d = 0.f;
        for (int t = lo; t <= hi; ++t) d += wtr[t]-wsr[t];
      }
      val = wsr[k] + 0.2f*d;
    }
    weff[(size_t)p*T_PAD + k] = f2bf(val);
  }
  if (threadIdx.x == 0 && p < P_LEN) bias[p] = bs[p] + bt[p];
}

// O[b,p,c] = relu( sum_k Weff[p,k] * X[b,k,c] + bias[p] )
// Block tile 128(p) x 128(c), K-step 32, 4 waves (2x2), wave tile 64x64,
// 4x4 fragments of v_mfma_f32_16x16x32_bf16 per wave.
__global__ __launch_bounds__(256, 2) void gemm_kernel(
    const float* __restrict__ x, const unsigned short* __restrict__ weff,
    const float* __restrict__ bias, float* __restrict__ out) {
  __shared__ unsigned short wA[BM*BK];   // [128][32] row-major (p, k)
  __shared__ unsigned short xT[BN*XP];   // [128][40] row-major (c, k)

  // XCD swizzle: each XCD gets 8 consecutive b; within XCD, p-tiles fastest
  const int bid = blockIdx.x;
  const int w   = (bid & 7)*672 + (bid >> 3);   // 5376 = 8*672
  const int b   = w / 84;                       // 84 = 6*14 tiles per batch
  const int rem = w % 84;
  const int ct  = rem / 6;
  const int pt  = rem % 6;
  const int p0  = pt * BM;
  const int c0  = ct * BN;

  const int tid  = threadIdx.x;
  const int lane = tid & 63;
  const int wid  = tid >> 6;
  const int wp   = wid >> 1;       // wave row (p)  0..1
  const int wc   = wid & 1;        // wave col (c)  0..1
  const int l16  = lane & 15;
  const int lg   = lane >> 4;

  const float* xb = x + (size_t)b * T_SEQ * C_LEN;

  // X staging: thread owns 2 adjacent c-columns x 8 k-rows
  const int cpair = lane * 2;      // 0..126
  const int kg    = wid;           // k-group 0..3 (k = kg*8 + j)
  const int cg    = c0 + cpair;
  const bool cok  = cg < C_LEN;    // C_LEN even => cg,cg+1 valid together

  f32x4 acc[4][4] = {};

  for (int kt = 0; kt < T_PAD; kt += BK) {
    // ---- stage Weff tile via global_load_lds (16B/lane, 2 issues) ----
#pragma unroll
    for (int i = 0; i < 2; ++i) {
      int o    = tid*16 + i*4096;          // byte offset in 8KB tile
      int row  = o >> 6;                   // 64B per row (32 bf16)
      int colb = o & 63;
      const unsigned short* src = weff + (size_t)(p0+row)*T_PAD + kt + (colb >> 1);
      unsigned short* dst = &wA[i*2048 + wid*512];   // wave-uniform base
      __builtin_amdgcn_global_load_lds(
          (const __attribute__((address_space(1))) unsigned int*)src,
          (__attribute__((address_space(3))) unsigned int*)dst, 16, 0, 0);
    }

    // ---- stage X tile: fp32 load, cvt bf16, transposed LDS write ----
    float2 v[8];
#pragma unroll
    for (int j = 0; j < 8; ++j) {
      int kk = kt + kg*8 + j;
      float2 t; t.x = 0.f; t.y = 0.f;
      if (cok && kk < T_SEQ)
        t = *(const float2*)(xb + (size_t)kk*C_LEN + cg);
      v[j] = t;
    }
    union { s16x8 vec; unsigned short u[8]; } pa, pb;
#pragma unroll
    for (int j = 0; j < 8; ++j) { pa.u[j] = f2bf(v[j].x); pb.u[j] = f2bf(v[j].y); }
    *(s16x8*)&xT[cpair*XP + kg*8]     = pa.vec;   // 16B aligned: cpair even
    *(s16x8*)&xT[(cpair+1)*XP + kg*8] = pb.vec;   // 80B pitch, 80%16==0

    __syncthreads();

    // ---- fragments + MFMA ----
    s16x8 af[4], bf_[4];
#pragma unroll
    for (int m = 0; m < 4; ++m)
      af[m] = *(const s16x8*)&wA[(wp*64 + m*16 + l16)*BK + lg*8];
#pragma unroll
    for (int n = 0; n < 4; ++n)
      bf_[n] = *(const s16x8*)&xT[(wc*64 + n*16 + l16)*XP + lg*8];
#pragma unroll
    for (int m = 0; m < 4; ++m)
#pragma unroll
      for (int n = 0; n < 4; ++n)
        acc[m][n] = __builtin_amdgcn_mfma_f32_16x16x32_bf16(
            af[m], bf_[n], acc[m][n], 0, 0, 0);

    __syncthreads();
  }

  // ---- epilogue: bias + relu + masked store ----
  // C/D layout (verified): row = lg*4 + reg, col = l16
  const size_t ob = (size_t)b * P_LEN * C_LEN;
#pragma unroll
  for (int m = 0; m < 4; ++m) {
    int pb0 = p0 + wp*64 + m*16 + lg*4;
    float bv[4];
#pragma unroll
    for (int r = 0; r < 4; ++r)
      bv[r] = (pb0 + r < P_LEN) ? bias[pb0 + r] : 0.f;
#pragma unroll
    for (int n = 0; n < 4; ++n) {
      int cc = c0 + wc*64 + n*16 + l16;
      if (cc < C_LEN) {
#pragma unroll
        for (int r = 0; r < 4; ++r) {
          if (pb0 + r < P_LEN) {
            float vv = acc[m][n][r] + bv[r];
            out[ob + (size_t)(pb0 + r)*C_LEN + cc] = fmaxf(vv, 0.f);
          }
        }
      }
    }
  }
}

extern "C" void kernel_launch(void* const* d_in, const int* in_sizes, int n_in,
                              void* d_out, int out_size, void* d_ws, size_t ws_size,
                              hipStream_t stream) {
  (void)in_sizes; (void)n_in; (void)out_size; (void)ws_size;
  const float* x  = (const float*)d_in[0];
  const float* Ws = (const float*)d_in[1];
  const float* bs = (const float*)d_in[2];
  const float* Wt = (const float*)d_in[3];
  const float* bt = (const float*)d_in[4];
  float* out = (float*)d_out;

  unsigned short* weff = (unsigned short*)d_ws;               // [768][352] bf16
  float* bias = (float*)((char*)d_ws + (size_t)P_PAD*T_PAD*2); // [720] f32

  prep_kernel<<<dim3(P_PAD), dim3(128), 0, stream>>>(Ws, bs, Wt, bt, weff, bias);
  gemm_kernel<<<dim3(NB*6*14), dim3(256), 0, stream>>>(x, weff, bias, out);
}